// Round 10
// baseline (120.714 us; speedup 1.0000x reference)
//
#include <hip/hip_runtime.h>

#define N 1024
#define D 256

// ---------------- prep ----------------
// 128 blocks x 8 rows, LDS-staged: coalesced float4 global loads, padded-LDS
// transpose, coalesced 8B stores.
#define RI 8
#define LDW 260

__global__ __launch_bounds__(256) void prep3(
    const float* __restrict__ muX, const float* __restrict__ ls,
    float2* __restrict__ msT2) {
  const int i0 = blockIdx.x * RI;
  const int t = threadIdx.x;
  __shared__ float smu[RI][LDW];
  __shared__ float ssg[RI][LDW];
  __shared__ float sred[RI][32];
  __shared__ float rden[RI];
  const float4* mu4 = (const float4*)(muX + (size_t)i0 * D);
  const float4* ls4 = (const float4*)(ls + (size_t)i0 * D);
#pragma unroll
  for (int u = 0; u < 2; ++u) {
    const int idx = u * 256 + t;
    const int row = idx >> 6, c4 = idx & 63;
    const float4 v = mu4[idx];
    *(float4*)&smu[row][c4 * 4] = v;
    const float4 e = ls4[idx];
    float4 x;
    x.x = __expf(e.x) + 5e-11f; x.y = __expf(e.y) + 5e-11f;  // eps folded
    x.z = __expf(e.z) + 5e-11f; x.w = __expf(e.w) + 5e-11f;
    *(float4*)&ssg[row][c4 * 4] = x;
  }
  __syncthreads();
  {
    const int r = t >> 5, q = t & 31;
    float s = 0.f;
#pragma unroll
    for (int k = 0; k < 8; ++k) {
      const float v = smu[r][q + 32 * k];
      s = fmaf(v, v, s);
    }
    sred[r][q] = s;
  }
  __syncthreads();
  if (t < RI) {
    float tot = 0.f;
    for (int u = 0; u < 32; ++u) tot += sred[t][u];
    rden[t] = 1.0f / fmaxf(sqrtf(tot), 1e-12f);  // F.normalize eps
  }
  __syncthreads();
#pragma unroll
  for (int pass = 0; pass < 8; ++pass) {
    const int f = pass * 256 + t;
    const int b = f & 1, il = (f >> 1) & 7, g = f >> 4;
    const int d = 2 * g + b;
    msT2[((size_t)g * N + i0 + il) * 2 + b] =
        make_float2(smu[il][d] * rden[il], ssg[il][d]);
  }
}

// ---------------- pair ----------------
// R5 shape (triangular 2x128 tiles, per-lane j float4, ln via running
// product) with the latency structure fixed:
//  (a) i-data (4KB) staged to LDS in a prologue -> NO s_loads in the hot
//      loop. R3..R9's plateau: i s_loads force lgkmcnt(0) full drains that
//      serialize every unroll chunk against ~900cy memory latency (SMEM
//      waits are all-or-nothing), capping per-wave duty at ~26%.
//  (b) depth-8 double-buffered j-prefetch in named VGPRs: chunk c+1's 8
//      loads are in flight during chunk c's ~800cy of compute -> <=~100cy
//      exposed per chunk.
#define UPD(jv, iv, k)                                           \
  {                                                              \
    const float s0 = (iv).y + (jv).y;                            \
    const float t0 = (iv).x - (jv).x;                            \
    acc[k] = fmaf(t0 * t0, __builtin_amdgcn_rcpf(s0), acc[k]);   \
    p[k] *= s0;                                                  \
    const float s1 = (iv).w + (jv).w;                            \
    const float t1 = (iv).z - (jv).z;                            \
    acc[k] = fmaf(t1 * t1, __builtin_amdgcn_rcpf(s1), acc[k]);   \
    p[k] *= s1;                                                  \
  }

#define STEP(jv, g, odd)                                         \
  {                                                              \
    const float4 iv0 = sI[2 * (g)];                              \
    const float4 iv1 = sI[2 * (g) + 1];                          \
    UPD(jv, iv0, 0)                                              \
    UPD(jv, iv1, 1)                                              \
    if (odd) {                                                   \
      for (int k = 0; k < 2; ++k) {                              \
        const int bb = __float_as_int(p[k]);                     \
        ea[k] += bb >> 23;                                       \
        p[k] = __int_as_float((bb & 0x007fffff) | 0x3f800000);   \
      }                                                          \
    }                                                            \
  }

#define CHUNK(r0, r1, r2, r3, r4, r5, r6, r7, g0)                \
  STEP(r0, (g0) + 0, 0) STEP(r1, (g0) + 1, 1)                    \
  STEP(r2, (g0) + 2, 0) STEP(r3, (g0) + 3, 1)                    \
  STEP(r4, (g0) + 4, 0) STEP(r5, (g0) + 5, 1)                    \
  STEP(r6, (g0) + 6, 0) STEP(r7, (g0) + 7, 1)

#define LOADC(r0, r1, r2, r3, r4, r5, r6, r7, g0)                \
  r0 = pj[(size_t)((g0) + 0) * N]; r1 = pj[(size_t)((g0) + 1) * N]; \
  r2 = pj[(size_t)((g0) + 2) * N]; r3 = pj[(size_t)((g0) + 3) * N]; \
  r4 = pj[(size_t)((g0) + 4) * N]; r5 = pj[(size_t)((g0) + 5) * N]; \
  r6 = pj[(size_t)((g0) + 6) * N]; r7 = pj[(size_t)((g0) + 7) * N];

__global__ __launch_bounds__(128) void pair_kernel(
    const float4* __restrict__ msT4, float* __restrict__ out) {
  int L = blockIdx.x;
  int js = 0, base = 0;  // slab js has 64*(js+1) row-tiles of 2 rows
  while (L >= base + 64 * (js + 1)) { base += 64 * (js + 1); ++js; }
  const int ib = L - base;
  const int j0 = js * 128, i0 = ib * 2;
  const bool diag = (ib >= js * 64);  // tile straddles the diagonal
  const int j = j0 + threadIdx.x;

  // prologue: stage this block's i-data (128 g x 2 rows x 16B = 4KB) to LDS
  __shared__ float4 sI[256];
  {
    const int t = threadIdx.x;  // t = g
    sI[2 * t] = msT4[(size_t)t * N + i0];
    sI[2 * t + 1] = msT4[(size_t)t * N + i0 + 1];
  }
  __syncthreads();

  const float4* __restrict__ pj = msT4 + j;

  float acc[2] = {0.f, 0.f};
  float p[2] = {1.f, 1.f};
  int ea[2] = {0, 0};

  float4 a0, a1, a2, a3, a4, a5, a6, a7;
  float4 b0, b1, b2, b3, b4, b5, b6, b7;
  LOADC(a0, a1, a2, a3, a4, a5, a6, a7, 0)
  LOADC(b0, b1, b2, b3, b4, b5, b6, b7, 8)

  for (int c = 0; c < 16; c += 2) {
    const int g0 = c * 8;
    CHUNK(a0, a1, a2, a3, a4, a5, a6, a7, g0)
    if (c + 2 < 16) { LOADC(a0, a1, a2, a3, a4, a5, a6, a7, g0 + 16) }
    CHUNK(b0, b1, b2, b3, b4, b5, b6, b7, g0 + 8)
    if (c + 3 < 16) { LOADC(b0, b1, b2, b3, b4, b5, b6, b7, g0 + 24) }
  }

  constexpr float LN2 = 0.6931471805599453f;
  float v[2];
#pragma unroll
  for (int k = 0; k < 2; ++k) {
    const float lg2 = (float)(ea[k] - 127 * (D / 4)) + __log2f(p[k]);
    v[k] = -(acc[k] + LN2 * lg2);
  }

  if (!diag) {  // strictly-upper tile: unmasked direct + mirror writes
    out[(size_t)i0 * N + j] = v[0];
    out[(size_t)(i0 + 1) * N + j] = v[1];
    *(float2*)(out + (size_t)j * N + i0) = make_float2(v[0], v[1]);
  } else {  // diagonal tile: per-element masks
#pragma unroll
    for (int k = 0; k < 2; ++k) {
      const int i = i0 + k;
      if (j >= i) out[(size_t)i * N + j] = v[k];
      if (j > i) out[(size_t)j * N + i] = v[k];
    }
  }
}

extern "C" void kernel_launch(void* const* d_in, const int* in_sizes, int n_in,
                              void* d_out, int out_size, void* d_ws, size_t ws_size,
                              hipStream_t stream) {
  const float* muX = (const float*)d_in[0];
  const float* ls  = (const float*)d_in[1];
  float* out = (float*)d_out;
  float2* msT2 = (float2*)d_ws;  // [D/2][N] packed (mu,sig,mu,sig) = 2 MB
  prep3<<<dim3(N / RI), dim3(256), 0, stream>>>(muX, ls, msT2);
  const int nblocks = 64 * (8 * 9 / 2);  // 2304 triangular 2x128 tiles
  pair_kernel<<<dim3(nblocks), dim3(128), 0, stream>>>((const float4*)msT2,
                                                       out);
}